// Round 1
// 67.430 us; speedup vs baseline: 1.0040x; 1.0040x over previous
//
#include <hip/hip_runtime.h>
#include <math.h>

#define NQ 10
#define BATCH 4096

// ============================================================================
// Heisenberg-picture evaluation (verified bit-exact in R3). Per sample:
//   <Z_w> = <prod| Ring0^+ [ (x)_{b in S_w} M_b ] Ring0 |prod>
//   |prod> = (x)_w (Rot0_w RY(x_w))|0>   (per-wire Bloch vector, sample-dep)
//   M_b   = Rot1_b^+ Z Rot1_b = cz Z + cx X + cy Y (batch-uniform)
//   S_w   = ring-1-conjugated Z-string masks (compile-time)
// Ring-0 conjugation via compile-time template recursion; symplectic sign.
// Labels: I=0, X=1, Z=2, Y=3 (bit0 = x-part, bit1 = z-part)
//
// R5: parallelism was the bottleneck (64 blocks on 256 CUs, 1 wave/SIMD,
//     252-leaf serial tree per wave). Split the two 243-leaf observables at
//     their natural template seams (sum9 / top2 summands, preserving fp add
//     order => bit-exact) and spread over a 64x4 = 256-block grid, one
//     ~81-leaf subtree per wave, partials to d_ws; a second tiny kernel
//     combines partials + MLP head. Critical path/wave: 252 -> 81 leaves,
//     CU coverage: 64 -> 256.
// ============================================================================

struct CR { int c, t, flip; };
__host__ __device__ constexpr CR cnot_conj(int lc, int lt) {
    const int xc = lc & 1, zc = (lc >> 1) & 1;
    const int xt = lt & 1, zt = (lt >> 1) & 1;
    const int flip = xc & zt & ((xt ^ zc) ^ 1);
    const int nxt = xt ^ xc;
    const int nzc = zc ^ zt;
    return { (nzc << 1) | xc, (zt << 1) | nxt, flip };
}

template<int SM, int K, int L1, int L0, int F>
__device__ __forceinline__ float chain(const float (&B)[NQ][4], const float (&C)[NQ][4], float p) {
    if constexpr (K == 0) {
        constexpr CR r = cnot_conj(L0, L1);     // H0: c=0, t=1
        float v = p;
        if constexpr (r.t != 0) v *= B[1][r.t];
        if constexpr (r.c != 0) v *= B[0][r.c];
        if constexpr (F ^ r.flip) return -v; else return v;
    } else if constexpr ((SM >> K) & 1) {
        float s = 0.f;
        {   constexpr CR r = cnot_conj(1, L1);  // sigma_K = X
            float p2 = p * C[K][1];
            if constexpr (r.t != 0) p2 *= B[K + 1][r.t];
            s += chain<SM, K - 1, r.c, L0, F ^ r.flip>(B, C, p2); }
        {   constexpr CR r = cnot_conj(2, L1);  // sigma_K = Z
            float p2 = p * C[K][2];
            if constexpr (r.t != 0) p2 *= B[K + 1][r.t];
            s += chain<SM, K - 1, r.c, L0, F ^ r.flip>(B, C, p2); }
        {   constexpr CR r = cnot_conj(3, L1);  // sigma_K = Y
            float p2 = p * C[K][3];
            if constexpr (r.t != 0) p2 *= B[K + 1][r.t];
            s += chain<SM, K - 1, r.c, L0, F ^ r.flip>(B, C, p2); }
        return s;
    } else {
        constexpr CR r = cnot_conj(0, L1);      // sigma_K = I
        float p2 = p;
        if constexpr (r.t != 0) p2 *= B[K + 1][r.t];
        return chain<SM, K - 1, r.c, L0, F ^ r.flip>(B, C, p2);
    }
}

template<int SM, int S0, int S9>
__device__ __forceinline__ float top2(const float (&B)[NQ][4], const float (&C)[NQ][4]) {
    constexpr CR r = cnot_conj(S9, S0);         // H9: c=9, t=0
    float p = 1.f;
    if constexpr (S0 != 0) p *= C[0][S0];
    if constexpr (S9 != 0) p *= C[9][S9];
    return chain<SM, 8, r.c, r.t, r.flip>(B, C, p);
}
template<int SM, int S0>
__device__ __forceinline__ float sum9(const float (&B)[NQ][4], const float (&C)[NQ][4]) {
    if constexpr ((SM >> 9) & 1)
        return top2<SM, S0, 1>(B, C) + top2<SM, S0, 2>(B, C) + top2<SM, S0, 3>(B, C);
    else
        return top2<SM, S0, 0>(B, C);
}
template<int SM>
__device__ __forceinline__ float obs_eval(const float (&B)[NQ][4], const float (&C)[NQ][4]) {
    if constexpr (SM & 1)
        return sum9<SM, 1>(B, C) + sum9<SM, 2>(B, C) + sum9<SM, 3>(B, C);
    else
        return sum9<SM, 0>(B, C);
}

// ---------------------------------------------------------------------------
// Kernel 1: per-(sample-group, obs-chunk) subtree evaluation.
// grid.x = 64 sample groups * 4 obs chunks = 256 blocks; 256 thr = 4 waves.
// Wave (ob, g) -> partial slot ob*4+g in zpart[slot][sample]:
//   ob0: S8a S8b S8c (81 each) + S2(9)      -> z8 = p0+p1+p2, z2 = p3
//   ob1: S9a S9b S9c (81 each) + S3(9)      -> z9 = p4+p5+p6, z3 = p7
//   ob2: S0(81) S1(81) S4(27) S5(27)        -> p8..p11
//   ob3: S6(81) S7(81) idle idle            -> p12, p13
// Max 81 leaves per wave everywhere -> balanced block durations.
// ---------------------------------------------------------------------------
__global__ __launch_bounds__(256) void tree_kernel(
    const float* __restrict__ x, const float* __restrict__ weights,
    float* __restrict__ zpart)
{
    __shared__ float U[60];          // per wire: R0 col0 (x3), R0 col2 (x3)
    __shared__ float CCs[40];        // per wire: {-, cx, cz, cy}

    const int t = threadIdx.x;

    // ---- batch-uniform precompute (lanes 0..9 of wave 0) ----
    if (t < NQ) {
        float phi0 = weights[t * 3 + 0], th0 = weights[t * 3 + 1], om0 = weights[t * 3 + 2];
        float phi1 = weights[(NQ + t) * 3 + 0], th1 = weights[(NQ + t) * 3 + 1];
        float cp, sp_, co, so, ct, st;
        sincosf(phi0, &sp_, &cp);
        sincosf(th0,  &st,  &ct);
        sincosf(om0,  &so,  &co);
        U[t * 6 + 0] = co * ct * cp - so * sp_;   // Rz(om)Ry(th)Rz(phi) ex
        U[t * 6 + 1] = so * ct * cp + co * sp_;
        U[t * 6 + 2] = -st * cp;
        U[t * 6 + 3] = co * st;                    // Rz(om)Ry(th) ez
        U[t * 6 + 4] = so * st;
        U[t * 6 + 5] = ct;
        float c1p, s1p, c1t, s1t;
        sincosf(phi1, &s1p, &c1p);
        sincosf(th1,  &s1t, &c1t);
        CCs[t * 4 + 1] = -s1t * c1p;   // X coeff
        CCs[t * 4 + 2] =  c1t;         // Z coeff
        CCs[t * 4 + 3] =  s1t * s1p;   // Y coeff
    }
    __syncthreads();

    const int g    = t >> 6;                    // wave id within block
    const int lane = t & 63;
    const int sg   = blockIdx.x >> 2;           // sample group (0..63)
    const int ob   = blockIdx.x & 3;            // obs chunk   (0..3)
    const int sample = sg * 64 + lane;

    // ---- per-wire Bloch vectors: B = sin(x)*col0 + cos(x)*col2 ----
    float B[NQ][4];
    float C[NQ][4];
    const float2* xp = (const float2*)(x + sample * NQ);
    #pragma unroll
    for (int h = 0; h < 5; ++h) {
        float2 xv = xp[h];
        #pragma unroll
        for (int q2 = 0; q2 < 2; ++q2) {
            int w = 2 * h + q2;
            float sx, cx;
            __sincosf(q2 ? xv.y : xv.x, &sx, &cx);
            B[w][0] = 1.f;
            B[w][1] = fmaf(sx, U[w * 6 + 0], cx * U[w * 6 + 3]);   // <X>
            B[w][3] = fmaf(sx, U[w * 6 + 1], cx * U[w * 6 + 4]);   // <Y>
            B[w][2] = fmaf(sx, U[w * 6 + 2], cx * U[w * 6 + 5]);   // <Z>
            C[w][0] = 1.f;
            C[w][1] = CCs[w * 4 + 1];
            C[w][2] = CCs[w * 4 + 2];
            C[w][3] = CCs[w * 4 + 3];
        }
    }

    // ---- subtree evaluation, one unit per wave (uniform branch) ----
    float v = 0.f;
    bool has = true;
    if (ob == 0) {
        if      (g == 0) v = sum9<0x155, 1>(B, C);     // z8 part a (81)
        else if (g == 1) v = sum9<0x155, 2>(B, C);     // z8 part b (81)
        else if (g == 2) v = sum9<0x155, 3>(B, C);     // z8 part c (81)
        else             v = obs_eval<0x005>(B, C);    // z2 (9)
    } else if (ob == 1) {
        if      (g == 0) v = top2<0x2AA, 0, 1>(B, C);  // z9 part a (81)
        else if (g == 1) v = top2<0x2AA, 0, 2>(B, C);  // z9 part b (81)
        else if (g == 2) v = top2<0x2AA, 0, 3>(B, C);  // z9 part c (81)
        else             v = obs_eval<0x00A>(B, C);    // z3 (9)
    } else if (ob == 2) {
        if      (g == 0) v = obs_eval<0x154>(B, C);    // z0 (81)
        else if (g == 1) v = obs_eval<0x2A8>(B, C);    // z1 (81)
        else if (g == 2) v = obs_eval<0x015>(B, C);    // z4 (27)
        else             v = obs_eval<0x02A>(B, C);    // z5 (27)
    } else {
        if      (g == 0) v = obs_eval<0x055>(B, C);    // z6 (81)
        else if (g == 1) v = obs_eval<0x0AA>(B, C);    // z7 (81)
        else             has = false;                  // idle waves
    }
    if (has)
        zpart[(ob * 4 + g) * BATCH + sample] = v;
}

// ---------------------------------------------------------------------------
// Kernel 2: combine partials (same fp add order as before => bit-exact) + MLP
// ---------------------------------------------------------------------------
__global__ __launch_bounds__(256) void mlp_kernel(
    const float* __restrict__ zpart,
    const float* __restrict__ w1, const float* __restrict__ b1,
    const float* __restrict__ w2, const float* __restrict__ b2,
    float* __restrict__ out)
{
    const int s = blockIdx.x * 256 + threadIdx.x;

    float z[NQ];
    z[8] = (zpart[0 * BATCH + s] + zpart[1 * BATCH + s]) + zpart[2 * BATCH + s];
    z[2] =  zpart[3 * BATCH + s];
    z[9] = (zpart[4 * BATCH + s] + zpart[5 * BATCH + s]) + zpart[6 * BATCH + s];
    z[3] =  zpart[7 * BATCH + s];
    z[0] =  zpart[8 * BATCH + s];
    z[1] =  zpart[9 * BATCH + s];
    z[4] =  zpart[10 * BATCH + s];
    z[5] =  zpart[11 * BATCH + s];
    z[6] =  zpart[12 * BATCH + s];
    z[7] =  zpart[13 * BATCH + s];

    float acc2 = b2[0];
    #pragma unroll
    for (int j = 0; j < 8; ++j) {
        float h = b1[j];
        #pragma unroll
        for (int w = 0; w < NQ; ++w)
            h = fmaf(z[w], w1[j * NQ + w], h);
        h = fmaxf(h, 0.f);
        acc2 = fmaf(h, w2[j], acc2);
    }
    out[s] = 1.f / (1.f + __expf(-acc2));
}

extern "C" void kernel_launch(void* const* d_in, const int* in_sizes, int n_in,
                              void* d_out, int out_size, void* d_ws, size_t ws_size,
                              hipStream_t stream) {
    const float* x       = (const float*)d_in[0];
    const float* weights = (const float*)d_in[1];
    const float* w1      = (const float*)d_in[2];
    const float* b1      = (const float*)d_in[3];
    const float* w2      = (const float*)d_in[4];
    const float* b2      = (const float*)d_in[5];
    float* out   = (float*)d_out;
    float* zpart = (float*)d_ws;                 // 14 * 4096 * 4 B = 229 KB

    tree_kernel<<<64 * 4, 256, 0, stream>>>(x, weights, zpart);
    mlp_kernel<<<BATCH / 256, 256, 0, stream>>>(zpart, w1, b1, w2, b2, out);
}